// Round 5
// baseline (332.254 us; speedup 1.0000x reference)
//
#include <hip/hip_runtime.h>

constexpr int NQ = 512;
constexpr int NKV = 512;
constexpr int Hh = 16;
constexpr int Dd = 256;

// C = A @ W^T + bias. M=4096, N=256, K=256. BM=BN=64, BK=64.
__global__ __launch_bounds__(256) void gemm_bias(
    const float* __restrict__ A, const float* __restrict__ W,
    const float* __restrict__ bias, float* __restrict__ C) {
  __shared__ float As[64][68];
  __shared__ float Ws[64][68];
  const int t = threadIdx.x;
  const int tx = t & 15, ty = t >> 4;
  const int m0 = blockIdx.x * 64, n0 = blockIdx.y * 64;

  float acc[4][4] = {};
  float4 av[4], wv[4];

#pragma unroll
  for (int i = 0; i < 4; ++i) {
    const int flat = i * 256 + t;
    const int r = flat >> 4, c4 = (flat & 15) << 2;
    av[i] = *(const float4*)(A + (size_t)(m0 + r) * 256 + c4);
    wv[i] = *(const float4*)(W + (size_t)(n0 + r) * 256 + c4);
  }

  for (int kb = 0; kb < 4; ++kb) {
#pragma unroll
    for (int i = 0; i < 4; ++i) {
      const int flat = i * 256 + t;
      const int r = flat >> 4, c4 = (flat & 15) << 2;
      As[c4 + 0][r] = av[i].x; As[c4 + 1][r] = av[i].y;
      As[c4 + 2][r] = av[i].z; As[c4 + 3][r] = av[i].w;
      Ws[c4 + 0][r] = wv[i].x; Ws[c4 + 1][r] = wv[i].y;
      Ws[c4 + 2][r] = wv[i].z; Ws[c4 + 3][r] = wv[i].w;
    }
    __syncthreads();
    if (kb < 3) {
#pragma unroll
      for (int i = 0; i < 4; ++i) {
        const int flat = i * 256 + t;
        const int r = flat >> 4, c4 = (flat & 15) << 2;
        av[i] = *(const float4*)(A + (size_t)(m0 + r) * 256 + (kb + 1) * 64 + c4);
        wv[i] = *(const float4*)(W + (size_t)(n0 + r) * 256 + (kb + 1) * 64 + c4);
      }
    }
#pragma unroll 16
    for (int k = 0; k < 64; ++k) {
      float a_[4], w_[4];
      *(float4*)a_ = *(const float4*)&As[k][ty << 2];
      *(float4*)w_ = *(const float4*)&Ws[k][tx << 2];
#pragma unroll
      for (int i = 0; i < 4; ++i)
#pragma unroll
        for (int j = 0; j < 4; ++j)
          acc[i][j] = fmaf(a_[i], w_[j], acc[i][j]);
    }
    if (kb < 3) __syncthreads();
  }

  const float4 bv = *(const float4*)(bias + n0 + (tx << 2));
  const float bb[4] = {bv.x, bv.y, bv.z, bv.w};
#pragma unroll
  for (int i = 0; i < 4; ++i) {
    float4 cv;
    cv.x = acc[i][0] + bb[0]; cv.y = acc[i][1] + bb[1];
    cv.z = acc[i][2] + bb[2]; cv.w = acc[i][3] + bb[3];
    *(float4*)(C + (size_t)(m0 + (ty << 2) + i) * 256 + n0 + (tx << 2)) = cv;
  }
}

// Fused masked softmax + per-head aggregation + L2 rescale. v6:
// = v5 pipeline (P via global_load_lds one round ahead, E double-buffered,
// ONE raw barrier/round with counted vmcnt(3)), with the FMA phase split
// into k-row PAIRS so only p0,p1 (8 regs) + float2 e-slice (2) are live
// at once instead of p0-p3 + e4 (20). Peak live regs ~52 < 64 tier ->
// no scratch spill (v5 spilled ~11 dwords/thread/round = 181 MB HBM
// writeback; allocator refuses >64 VGPR regardless of waves_per_eu).
// Per-accumulator k-order for o[] unchanged (rows 0,1,2,3 per qi).
__global__ __launch_bounds__(512, 4) void attn_fused(
    const float* __restrict__ msg, const int* __restrict__ adj,
    const float* __restrict__ proj, float* __restrict__ attn_out) {
  __shared__ float Psh[4][8][256];        // 32 KB: [oct][k][col], linear (DMA dest)
  __shared__ float Esh[2][4][8][16][12];  // 48 KB: [buf][oct][q][h^q][k(8 used)]

  const int t    = threadIdx.x;
  const int lane = t & 63;
  const int w    = t >> 6;      // wave 0..7
  const int oct  = w >> 1;      // k-quarter for FMA
  const int qh   = w & 1;       // q-half for FMA
  const int h    = lane >> 2;
  const int d4   = lane & 3;
  const int col  = lane << 2;   // = h*16 + d4*4
  const int q0   = blockIdx.x * 8;
  const int b    = blockIdx.y;

  // E-production decomposition
  const int p_h4  = t & 3;
  const int p_q   = (t >> 2) & 7;
  const int p_oct = (t >> 5) & 3;
  const int p_jp  = t >> 7;     // 0..3 (k-pair)

  const float* mrow  = msg + ((size_t)(b * NQ + q0 + p_q) * NKV) * Hh + p_h4 * 4;
  const int*   arow  = adj + (size_t)(b * NQ + q0 + p_q) * NKV;
  const float* pbase = proj + (size_t)b * NKV * Dd;

  float4 o[4] = {};
  float s[4] = {}, r[4] = {};

  float4 mA0, mA1, mB0, mB1;
  int2 aA, aB;

#define STAGE_P(RD)                                                            \
  _Pragma("unroll")                                                            \
  for (int i = 0; i < 4; ++i) {                                                \
    const float* g = pbase + (size_t)(i * 128 + (RD) * 8 + w) * Dd + (lane << 2); \
    __builtin_amdgcn_global_load_lds(                                          \
        (const __attribute__((address_space(1))) unsigned int*)g,              \
        (__attribute__((address_space(3))) unsigned int*)&Psh[i][w][0],        \
        16, 0, 0);                                                             \
  }

  {  // prologue: round-0 messages, then round-0 P DMA
    const int kg = p_oct * 128 + p_jp * 2;
    mA0 = *(const float4*)(mrow + (size_t)kg * Hh);
    mA1 = *(const float4*)(mrow + (size_t)(kg + 1) * Hh);
    aA = *(const int2*)(arow + kg);
    STAGE_P(0)
  }

// One k-row PAIR: 2 P rows (8 regs) x 4 qi, e as float2 slice (2 regs).
#define FMA_PAIR(BUF, K0)                                                      \
  {                                                                            \
    const float4 p0 = *(const float4*)&Psh[oct][(K0) + 0][col];                \
    const float4 p1 = *(const float4*)&Psh[oct][(K0) + 1][col];                \
    _Pragma("unroll")                                                          \
    for (int qi = 0; qi < 4; ++qi) {                                           \
      const int ql = qh * 4 + qi;                                              \
      const float2 e2 = *(const float2*)&Esh[BUF][oct][ql][h ^ ql][K0];        \
      s[qi] += e2.x + e2.y;                                                    \
      r[qi] = fmaf(e2.x, e2.x, fmaf(e2.y, e2.y, r[qi]));                       \
      o[qi].x = fmaf(e2.x, p0.x, o[qi].x);                                     \
      o[qi].y = fmaf(e2.x, p0.y, o[qi].y);                                     \
      o[qi].z = fmaf(e2.x, p0.z, o[qi].z);                                     \
      o[qi].w = fmaf(e2.x, p0.w, o[qi].w);                                     \
      o[qi].x = fmaf(e2.y, p1.x, o[qi].x);                                     \
      o[qi].y = fmaf(e2.y, p1.y, o[qi].y);                                     \
      o[qi].z = fmaf(e2.y, p1.z, o[qi].z);                                     \
      o[qi].w = fmaf(e2.y, p1.w, o[qi].w);                                     \
    }                                                                          \
  }

#define ATTN_ROUND(RD, BUF, MC0, MC1, AC, MN0, MN1, AN)                        \
  {                                                                            \
    if ((RD) < 15) { /* next-round msg prefetch, ~600cyc ahead of use */       \
      const int kg = p_oct * 128 + ((RD) + 1) * 8 + p_jp * 2;                  \
      MN0 = *(const float4*)(mrow + (size_t)kg * Hh);                          \
      MN1 = *(const float4*)(mrow + (size_t)(kg + 1) * Hh);                    \
      AN = *(const int2*)(arow + kg);                                          \
    }                                                                          \
    {                                                                          \
      float e0[4], e1[4];                                                      \
      e0[0] = AC.x > 0 ? __expf(MC0.x) : 0.f;                                  \
      e0[1] = AC.x > 0 ? __expf(MC0.y) : 0.f;                                  \
      e0[2] = AC.x > 0 ? __expf(MC0.z) : 0.f;                                  \
      e0[3] = AC.x > 0 ? __expf(MC0.w) : 0.f;                                  \
      e1[0] = AC.y > 0 ? __expf(MC1.x) : 0.f;                                  \
      e1[1] = AC.y > 0 ? __expf(MC1.y) : 0.f;                                  \
      e1[2] = AC.y > 0 ? __expf(MC1.z) : 0.f;                                  \
      e1[3] = AC.y > 0 ? __expf(MC1.w) : 0.f;                                  \
      _Pragma("unroll")                                                        \
      for (int i = 0; i < 4; ++i) {                                            \
        const int h2 = (p_h4 * 4 + i) ^ p_q;                                   \
        *(float2*)&Esh[BUF][p_oct][p_q][h2][p_jp * 2] =                        \
            make_float2(e0[i], e1[i]);                                         \
      }                                                                        \
    }                                                                          \
    if ((RD) < 15) {                                                           \
      asm volatile("s_waitcnt vmcnt(3)" ::: "memory");  /* P(RD) done */       \
    } else {                                                                   \
      asm volatile("s_waitcnt vmcnt(0)" ::: "memory");                         \
    }                                                                          \
    asm volatile("s_waitcnt lgkmcnt(0)" ::: "memory");  /* publish E */        \
    __builtin_amdgcn_s_barrier();                                              \
    __builtin_amdgcn_sched_barrier(0);                                         \
    __builtin_amdgcn_s_setprio(1);                                             \
    FMA_PAIR(BUF, 0)                                                           \
    FMA_PAIR(BUF, 2)                                                           \
    FMA_PAIR(BUF, 4)                                                           \
    FMA_PAIR(BUF, 6)                                                           \
    __builtin_amdgcn_s_setprio(0);                                             \
    __syncthreads();  /* Psh WAR fence; only msg loads left in vmcnt */        \
    if ((RD) < 15) { STAGE_P((RD) + 1) }                                       \
  }

  for (int rr = 0; rr < 8; ++rr) {
    const int rdE = rr * 2;
    ATTN_ROUND(rdE,     0, mA0, mA1, aA, mB0, mB1, aB);
    ATTN_ROUND(rdE + 1, 1, mB0, mB1, aB, mA0, mA1, aA);
  }
#undef ATTN_ROUND
#undef FMA_PAIR
#undef STAGE_P

  // ---- epilogue: tree-reduce partial (o,s,r) over the 4 k-quarters ----
  float*  base = &Esh[0][0][0][0][0];
  float4* Ro = (float4*)base;     // 16 KB (1024 float4)
  float*  Rs = base + 4096;       // 256 floats
  float*  Rr = base + 4352;       // 256 floats

  __syncthreads();
  if (w >= 4) {  // oct 2,3 write regions 0..3
    const int reg = w - 4;
#pragma unroll
    for (int qi = 0; qi < 4; ++qi) {
      Ro[(reg * 4 + qi) * 64 + lane] = o[qi];
      if (d4 == 0) {
        Rs[(reg * 4 + qi) * 16 + h] = s[qi];
        Rr[(reg * 4 + qi) * 16 + h] = r[qi];
      }
    }
  }
  __syncthreads();
  if (w < 4) {
#pragma unroll
    for (int qi = 0; qi < 4; ++qi) {
      const float4 v = Ro[(w * 4 + qi) * 64 + lane];
      o[qi].x += v.x; o[qi].y += v.y; o[qi].z += v.z; o[qi].w += v.w;
      s[qi] += Rs[(w * 4 + qi) * 16 + h];
      r[qi] += Rr[(w * 4 + qi) * 16 + h];
    }
  }
  __syncthreads();
  if (w == 2 || w == 3) {  // oct 1 writes regions 0,1
    const int reg = w - 2;
#pragma unroll
    for (int qi = 0; qi < 4; ++qi) {
      Ro[(reg * 4 + qi) * 64 + lane] = o[qi];
      if (d4 == 0) {
        Rs[(reg * 4 + qi) * 16 + h] = s[qi];
        Rr[(reg * 4 + qi) * 16 + h] = r[qi];
      }
    }
  }
  __syncthreads();
  if (w < 2) {
#pragma unroll
    for (int qi = 0; qi < 4; ++qi) {
      const float4 v = Ro[(w * 4 + qi) * 64 + lane];
      o[qi].x += v.x; o[qi].y += v.y; o[qi].z += v.z; o[qi].w += v.w;
      const float st = s[qi] + Rs[(w * 4 + qi) * 16 + h];
      const float rt = r[qi] + Rr[(w * 4 + qi) * 16 + h];
      const float wgt = sqrtf(rt) / (st * st);
      float4 u;
      u.x = o[qi].x * wgt; u.y = o[qi].y * wgt;
      u.z = o[qi].z * wgt; u.w = o[qi].w * wgt;
      const int q = q0 + w * 4 + qi;
      *(float4*)(attn_out + (size_t)(b * NQ + q) * Dd + col) = u;
    }
  }
}

extern "C" void kernel_launch(void* const* d_in, const int* in_sizes, int n_in,
                              void* d_out, int out_size, void* d_ws, size_t ws_size,
                              hipStream_t stream) {
  const float* v_inv    = (const float*)d_in[0];
  const float* messages = (const float*)d_in[1];
  const int*   adj      = (const int*)d_in[2];
  const float* W_in     = (const float*)d_in[3];
  const float* b_in     = (const float*)d_in[4];
  const float* W_out    = (const float*)d_in[5];
  const float* b_out    = (const float*)d_in[6];
  float* out = (float*)d_out;

  float* proj = (float*)d_ws;                      // 4 MB [B,NKV,D]
  float* attn = proj + (size_t)8 * NKV * Dd;       // 4 MB [B,NQ,D]

  dim3 gg(64, 4);
  gemm_bias<<<gg, 256, 0, stream>>>(v_inv, W_in, b_in, proj);
  attn_fused<<<dim3(64, 8), 512, 0, stream>>>(messages, adj, proj, attn);
  gemm_bias<<<gg, 256, 0, stream>>>(attn, W_out, b_out, out);
}

// Round 6
// 260.893 us; speedup vs baseline: 1.2735x; 1.2735x over previous
//
#include <hip/hip_runtime.h>

constexpr int NQ = 512;
constexpr int NKV = 512;
constexpr int Hh = 16;
constexpr int Dd = 256;

// C = A @ W^T + bias. M=4096, N=256, K=256. BM=BN=64, BK=64.
__global__ __launch_bounds__(256) void gemm_bias(
    const float* __restrict__ A, const float* __restrict__ W,
    const float* __restrict__ bias, float* __restrict__ C) {
  __shared__ float As[64][68];
  __shared__ float Ws[64][68];
  const int t = threadIdx.x;
  const int tx = t & 15, ty = t >> 4;
  const int m0 = blockIdx.x * 64, n0 = blockIdx.y * 64;

  float acc[4][4] = {};
  float4 av[4], wv[4];

#pragma unroll
  for (int i = 0; i < 4; ++i) {
    const int flat = i * 256 + t;
    const int r = flat >> 4, c4 = (flat & 15) << 2;
    av[i] = *(const float4*)(A + (size_t)(m0 + r) * 256 + c4);
    wv[i] = *(const float4*)(W + (size_t)(n0 + r) * 256 + c4);
  }

  for (int kb = 0; kb < 4; ++kb) {
#pragma unroll
    for (int i = 0; i < 4; ++i) {
      const int flat = i * 256 + t;
      const int r = flat >> 4, c4 = (flat & 15) << 2;
      As[c4 + 0][r] = av[i].x; As[c4 + 1][r] = av[i].y;
      As[c4 + 2][r] = av[i].z; As[c4 + 3][r] = av[i].w;
      Ws[c4 + 0][r] = wv[i].x; Ws[c4 + 1][r] = wv[i].y;
      Ws[c4 + 2][r] = wv[i].z; Ws[c4 + 3][r] = wv[i].w;
    }
    __syncthreads();
    if (kb < 3) {
#pragma unroll
      for (int i = 0; i < 4; ++i) {
        const int flat = i * 256 + t;
        const int r = flat >> 4, c4 = (flat & 15) << 2;
        av[i] = *(const float4*)(A + (size_t)(m0 + r) * 256 + (kb + 1) * 64 + c4);
        wv[i] = *(const float4*)(W + (size_t)(n0 + r) * 256 + (kb + 1) * 64 + c4);
      }
    }
#pragma unroll 16
    for (int k = 0; k < 64; ++k) {
      float a_[4], w_[4];
      *(float4*)a_ = *(const float4*)&As[k][ty << 2];
      *(float4*)w_ = *(const float4*)&Ws[k][tx << 2];
#pragma unroll
      for (int i = 0; i < 4; ++i)
#pragma unroll
        for (int j = 0; j < 4; ++j)
          acc[i][j] = fmaf(a_[i], w_[j], acc[i][j]);
    }
    if (kb < 3) __syncthreads();
  }

  const float4 bv = *(const float4*)(bias + n0 + (tx << 2));
  const float bb[4] = {bv.x, bv.y, bv.z, bv.w};
#pragma unroll
  for (int i = 0; i < 4; ++i) {
    float4 cv;
    cv.x = acc[i][0] + bb[0]; cv.y = acc[i][1] + bb[1];
    cv.z = acc[i][2] + bb[2]; cv.w = acc[i][3] + bb[3];
    *(float4*)(C + (size_t)(m0 + (ty << 2) + i) * 256 + n0 + (tx << 2)) = cv;
  }
}

// Fused masked softmax + per-head aggregation + L2 rescale. v7:
// Both P and E double-buffered; round = 16 k-rows (4 per oct); ONE
// __syncthreads per round (no inline asm, no raw barriers, runtime loop --
// the shape the compiler allocates without spilling; v3-v6's asm-walled
// macro bodies all spilled 180-400 MB scratch at the forced 64-VGPR tier).
// Round rd: stage P(rd+1)->Psh[nxt] (DMA, full-round latency cover),
// prefetch msg(rd+1)->regs, FMA(rd) from [cur], E(rd+1)->Esh[nxt], sync.
// Race audit: Psh/Esh[nxt] writers vs prior readers (round rd-1) separated
// by sync(rd-1); readers of [nxt] (round rd+1) separated by sync(rd) which
// also vmcnt-drains the DMA. s/r/o summation order identical to round-1
// (e4-grouped, k ascending) -> absmax must return to 2.441e-4 exactly.
__global__ __launch_bounds__(512, 4) void attn_fused(
    const float* __restrict__ msg, const int* __restrict__ adj,
    const float* __restrict__ proj, float* __restrict__ attn_out) {
  __shared__ float Psh[2][4][4][256];    // 32 KB: [buf][oct][kk][col], linear DMA dest
  __shared__ float Esh[2][4][8][16][4];  // 16 KB: [buf][oct][q][h^q][kk]

  const int t    = threadIdx.x;
  const int lane = t & 63;
  const int w    = t >> 6;      // wave 0..7
  const int oct  = w >> 1;      // k-quarter for FMA
  const int qh   = w & 1;       // q-half for FMA
  const int h    = lane >> 2;
  const int d4   = lane & 3;
  const int col  = lane << 2;   // = h*16 + d4*4
  const int q0   = blockIdx.x * 8;
  const int b    = blockIdx.y;

  // E-production decomposition: thread covers (oct, q, kk, h4..h4+3)
  const int p_h4  = t & 3;
  const int p_q   = (t >> 2) & 7;
  const int p_oct = (t >> 5) & 3;
  const int p_kk  = t >> 7;     // 0..3

  // P-staging rows for this wave (2 rows of 16 per round)
  const int sa = w * 2, sb = w * 2 + 1;
  const int sa_oct = sa >> 2, sa_kk = sa & 3;
  const int sb_oct = sb >> 2, sb_kk = sb & 3;

  const float* mrow  = msg + ((size_t)(b * NQ + q0 + p_q) * NKV) * Hh + p_h4 * 4;
  const int*   arow  = adj + (size_t)(b * NQ + q0 + p_q) * NKV;
  const float* pbase = proj + (size_t)b * NKV * Dd;

  float4 o[4] = {};
  float s[4] = {}, r[4] = {};

  float4 mv; int aa;

  // ---- prologue: msg(0) -> E(0) -> Esh[0]; P(0) -> Psh[0]; sync ----
  {
    const int kg = p_oct * 128 + p_kk;
    mv = *(const float4*)(mrow + (size_t)kg * Hh);
    aa = arow[kg];
    const float* ga = pbase + (size_t)(sa_oct * 128 + sa_kk) * Dd + (lane << 2);
    __builtin_amdgcn_global_load_lds(
        (const __attribute__((address_space(1))) unsigned int*)ga,
        (__attribute__((address_space(3))) unsigned int*)&Psh[0][sa_oct][sa_kk][0],
        16, 0, 0);
    const float* gb = pbase + (size_t)(sb_oct * 128 + sb_kk) * Dd + (lane << 2);
    __builtin_amdgcn_global_load_lds(
        (const __attribute__((address_space(1))) unsigned int*)gb,
        (__attribute__((address_space(3))) unsigned int*)&Psh[0][sb_oct][sb_kk][0],
        16, 0, 0);
    float e[4];
    e[0] = aa > 0 ? __expf(mv.x) : 0.f;
    e[1] = aa > 0 ? __expf(mv.y) : 0.f;
    e[2] = aa > 0 ? __expf(mv.z) : 0.f;
    e[3] = aa > 0 ? __expf(mv.w) : 0.f;
#pragma unroll
    for (int i = 0; i < 4; ++i)
      Esh[0][p_oct][p_q][(p_h4 * 4 + i) ^ p_q][p_kk] = e[i];
  }
  __syncthreads();

#pragma unroll 1
  for (int rd = 0; rd < 32; ++rd) {
    const int cur = rd & 1, nxt = cur ^ 1;
    if (rd < 31) {
      // stage P(rd+1) into the other buffer (WAR: its readers were round
      // rd-1, before sync(rd-1)); completion via sync(rd)'s vmcnt drain.
      const float* ga =
          pbase + (size_t)(sa_oct * 128 + (rd + 1) * 4 + sa_kk) * Dd + (lane << 2);
      __builtin_amdgcn_global_load_lds(
          (const __attribute__((address_space(1))) unsigned int*)ga,
          (__attribute__((address_space(3))) unsigned int*)&Psh[nxt][sa_oct][sa_kk][0],
          16, 0, 0);
      const float* gb =
          pbase + (size_t)(sb_oct * 128 + (rd + 1) * 4 + sb_kk) * Dd + (lane << 2);
      __builtin_amdgcn_global_load_lds(
          (const __attribute__((address_space(1))) unsigned int*)gb,
          (__attribute__((address_space(3))) unsigned int*)&Psh[nxt][sb_oct][sb_kk][0],
          16, 0, 0);
      // msg(rd+1) prefetch: consumed by E(rd+1) after the FMA phase below.
      const int kg = p_oct * 128 + (rd + 1) * 4 + p_kk;
      mv = *(const float4*)(mrow + (size_t)kg * Hh);
      aa = arow[kg];
    }

    // ---- FMA(rd): pair-wise P to keep peak live regs < 64 ----
    __builtin_amdgcn_s_setprio(1);
    {
      const float4 p0 = *(const float4*)&Psh[cur][oct][0][col];
      const float4 p1 = *(const float4*)&Psh[cur][oct][1][col];
#pragma unroll
      for (int qi = 0; qi < 4; ++qi) {
        const int ql = qh * 4 + qi;
        const float4 e4 = *(const float4*)&Esh[cur][oct][ql][h ^ ql][0];
        s[qi] += e4.x + e4.y + e4.z + e4.w;
        r[qi] = fmaf(e4.x, e4.x, fmaf(e4.y, e4.y,
                fmaf(e4.z, e4.z, fmaf(e4.w, e4.w, r[qi]))));
        o[qi].x = fmaf(e4.x, p0.x, o[qi].x);
        o[qi].y = fmaf(e4.x, p0.y, o[qi].y);
        o[qi].z = fmaf(e4.x, p0.z, o[qi].z);
        o[qi].w = fmaf(e4.x, p0.w, o[qi].w);
        o[qi].x = fmaf(e4.y, p1.x, o[qi].x);
        o[qi].y = fmaf(e4.y, p1.y, o[qi].y);
        o[qi].z = fmaf(e4.y, p1.z, o[qi].z);
        o[qi].w = fmaf(e4.y, p1.w, o[qi].w);
      }
    }
    {
      const float4 p2 = *(const float4*)&Psh[cur][oct][2][col];
      const float4 p3 = *(const float4*)&Psh[cur][oct][3][col];
#pragma unroll
      for (int qi = 0; qi < 4; ++qi) {
        const int ql = qh * 4 + qi;
        const float2 e2 = *(const float2*)&Esh[cur][oct][ql][h ^ ql][2];
        o[qi].x = fmaf(e2.x, p2.x, o[qi].x);
        o[qi].y = fmaf(e2.x, p2.y, o[qi].y);
        o[qi].z = fmaf(e2.x, p2.z, o[qi].z);
        o[qi].w = fmaf(e2.x, p2.w, o[qi].w);
        o[qi].x = fmaf(e2.y, p3.x, o[qi].x);
        o[qi].y = fmaf(e2.y, p3.y, o[qi].y);
        o[qi].z = fmaf(e2.y, p3.z, o[qi].z);
        o[qi].w = fmaf(e2.y, p3.w, o[qi].w);
      }
    }
    __builtin_amdgcn_s_setprio(0);

    // ---- E(rd+1) -> Esh[nxt] (WAR: readers were round rd-1) ----
    if (rd < 31) {
      float e[4];
      e[0] = aa > 0 ? __expf(mv.x) : 0.f;
      e[1] = aa > 0 ? __expf(mv.y) : 0.f;
      e[2] = aa > 0 ? __expf(mv.z) : 0.f;
      e[3] = aa > 0 ? __expf(mv.w) : 0.f;
#pragma unroll
      for (int i = 0; i < 4; ++i)
        Esh[nxt][p_oct][p_q][(p_h4 * 4 + i) ^ p_q][p_kk] = e[i];
    }
    __syncthreads();  // publishes Esh[nxt]; drains P(rd+1) DMA (full-round cover)
  }

  // ---- epilogue: tree-reduce partial (o,s,r) over the 4 k-quarters ----
  float4* Ro = (float4*)&Psh[0][0][0][0];  // 16 KB of 32 used
  float*  Rs = &Esh[0][0][0][0][0];        // 256 floats
  float*  Rr = Rs + 256;                   // 256 floats

  __syncthreads();
  if (w >= 4) {  // oct 2,3 write regions 0..3
    const int reg = w - 4;
#pragma unroll
    for (int qi = 0; qi < 4; ++qi) {
      Ro[(reg * 4 + qi) * 64 + lane] = o[qi];
      if (d4 == 0) {
        Rs[(reg * 4 + qi) * 16 + h] = s[qi];
        Rr[(reg * 4 + qi) * 16 + h] = r[qi];
      }
    }
  }
  __syncthreads();
  if (w < 4) {
#pragma unroll
    for (int qi = 0; qi < 4; ++qi) {
      const float4 v = Ro[(w * 4 + qi) * 64 + lane];
      o[qi].x += v.x; o[qi].y += v.y; o[qi].z += v.z; o[qi].w += v.w;
      s[qi] += Rs[(w * 4 + qi) * 16 + h];
      r[qi] += Rr[(w * 4 + qi) * 16 + h];
    }
  }
  __syncthreads();
  if (w == 2 || w == 3) {  // oct 1 writes regions 0,1
    const int reg = w - 2;
#pragma unroll
    for (int qi = 0; qi < 4; ++qi) {
      Ro[(reg * 4 + qi) * 64 + lane] = o[qi];
      if (d4 == 0) {
        Rs[(reg * 4 + qi) * 16 + h] = s[qi];
        Rr[(reg * 4 + qi) * 16 + h] = r[qi];
      }
    }
  }
  __syncthreads();
  if (w < 2) {
#pragma unroll
    for (int qi = 0; qi < 4; ++qi) {
      const float4 v = Ro[(w * 4 + qi) * 64 + lane];
      o[qi].x += v.x; o[qi].y += v.y; o[qi].z += v.z; o[qi].w += v.w;
      const float st = s[qi] + Rs[(w * 4 + qi) * 16 + h];
      const float rt = r[qi] + Rr[(w * 4 + qi) * 16 + h];
      const float wgt = sqrtf(rt) / (st * st);
      float4 u;
      u.x = o[qi].x * wgt; u.y = o[qi].y * wgt;
      u.z = o[qi].z * wgt; u.w = o[qi].w * wgt;
      const int q = q0 + w * 4 + qi;
      *(float4*)(attn_out + (size_t)(b * NQ + q) * Dd + col) = u;
    }
  }
}

extern "C" void kernel_launch(void* const* d_in, const int* in_sizes, int n_in,
                              void* d_out, int out_size, void* d_ws, size_t ws_size,
                              hipStream_t stream) {
  const float* v_inv    = (const float*)d_in[0];
  const float* messages = (const float*)d_in[1];
  const int*   adj      = (const int*)d_in[2];
  const float* W_in     = (const float*)d_in[3];
  const float* b_in     = (const float*)d_in[4];
  const float* W_out    = (const float*)d_in[5];
  const float* b_out    = (const float*)d_in[6];
  float* out = (float*)d_out;

  float* proj = (float*)d_ws;                      // 4 MB [B,NKV,D]
  float* attn = proj + (size_t)8 * NKV * Dd;       // 4 MB [B,NQ,D]

  dim3 gg(64, 4);
  gemm_bias<<<gg, 256, 0, stream>>>(v_inv, W_in, b_in, proj);
  attn_fused<<<dim3(64, 8), 512, 0, stream>>>(messages, adj, proj, attn);
  gemm_bias<<<gg, 256, 0, stream>>>(attn, W_out, b_out, out);
}